// Round 8
// baseline (91.234 us; speedup 1.0000x reference)
//
#include <hip/hip_runtime.h>
#include <math.h>
#include <limits.h>

namespace {

constexpr int B_ = 16;
constexpr int H_ = 512;
constexpr int W_ = 512;
constexpr int HW_ = H_ * W_;
constexpr int CAP_ = 4096;           // one slot per 8x8 sub-block per image
constexpr int NSEL_ = 500;
constexpr int NTILE_ = B_ * 256;     // 4096 tile blocks
constexpr int NPART_ = NTILE_ + B_;  // partial-sum slots

typedef float f32x4 __attribute__((ext_vector_type(4)));
typedef float f32x2 __attribute__((ext_vector_type(2)));

__device__ inline f32x4 ld4(const float* p) { return *(const f32x4*)p; }
__device__ inline f32x2 ld2(const float* p) { return *(const f32x2*)p; }

// 7-tap gaussian, sigma=1, normalized (matches reference's np.exp/sum)
__device__ constexpr float GW[7] = {
    0.004433048175243746f, 0.05400558262251428f, 0.24203622937611957f,
    0.3990502796522496f,  0.24203622937611957f, 0.05400558262251428f,
    0.004433048175243746f};

__device__ inline int reflect_i(int i, int n) {
  // jnp.pad mode='reflect': -1 -> 1, n -> n-2
  return i < 0 ? -i : (i > n - 1 ? 2 * (n - 1) - i : i);
}

// Shared per-pixel product math: BOTH interior and border paths use this,
// so cross-tile halo recomputation is bit-identical (same op order).
__device__ __forceinline__ void prod3(float q00, float q01, float q02,
                                      float q10, float q12,
                                      float q20, float q21, float q22,
                                      float& P0, float& P1, float& P2) {
  float dxr = (q02 - q00) + 2.f * (q12 - q10) + (q22 - q20);
  float dyr = (q20 - q00) + 2.f * (q21 - q01) + (q22 - q02);
  const float cc = 1.f / 64.f;  // sobel /8 twice, folded
  float t = dxr * cc, u = dyr * cc;
  P0 = t * dxr;
  P1 = u * dyr;
  P2 = t * dyr;
}

// LDS layout (phase-aliased):
//  A region: g_s[44][48] (phases 1-2)  -->  r_s[36][37] + c_s[32][32] (4-6)
//  wsum[16] after A; B: p_s[3][42][44]; C: v_s[3][36][44]. Total 50672 B.
constexpr int OFF_C = 5328;    // 36*37*4
constexpr int OFF_W = 9424;    // + 32*32*4
constexpr int OFF_P = 9488;    // + 64
constexpr int OFF_V = 31664;   // + 3*42*44*4
constexpr int SMEM_SZ = 50672; // + 3*36*44*4  -> 3 blocks/CU

// K1 (fused): gray -> sobel products -> gaussian blur -> min-eig response
// (36x36 incl. halo 2) -> 5x5 NMS -> 8x8 block max -> cand slots.
// Also sums a 1024-float chunk of scores' log1p(-p) terms (hidden under VALU).
__global__ __launch_bounds__(256) void k_main(const float* __restrict__ imgs,
                                              const float* __restrict__ scores,
                                              float* __restrict__ cand_val,
                                              int* __restrict__ cand_idx,
                                              double* __restrict__ part) {
  __shared__ __align__(16) char smem[SMEM_SZ];
  float (*g_s)[48] = reinterpret_cast<float (*)[48]>(smem);
  float (*r_s)[37] = reinterpret_cast<float (*)[37]>(smem);
  float (*c_s)[32] = reinterpret_cast<float (*)[32]>(smem + OFF_C);
  float* wsum = reinterpret_cast<float*>(smem + OFF_W);
  float (*p_s)[42][44] = reinterpret_cast<float (*)[42][44]>(smem + OFF_P);
  float (*v_s)[36][44] = reinterpret_cast<float (*)[36][44]>(smem + OFF_V);

  int bid = blockIdx.x;
  int bx = bid & 15, by = (bid >> 4) & 15, b = bid >> 8;
  int r0 = by * 32, c0 = bx * 32;
  int tid = threadIdx.x;
  const float* img = imgs + (size_t)b * 3 * HW_;

  // BCE base chunk: issue the load now, consume at the very end.
  f32x4 sc = ld4(scores + (size_t)bid * 1024 + tid * 4);

  bool interior = (bx >= 1 && bx <= 14 && by >= 1 && by <= 14);

  if (interior) {
    // Phase 1: gray, 44 rows x 12 f32x4 groups (cols c0-8..c0+39, 16B-aligned)
    for (int l = tid; l < 528; l += 256) {
      int row = l / 12, c4 = (l % 12) * 4;
      int o = (r0 - 6 + row) * W_ + (c0 - 8 + c4);
      f32x4 R = ld4(&img[o]);
      f32x4 G = ld4(&img[HW_ + o]);
      f32x4 Bl = ld4(&img[2 * HW_ + o]);
      f32x4 gray = 0.299f * R + 0.587f * G + 0.114f * Bl;
      *(f32x4*)&g_s[row][c4] = gray;
    }
    __syncthreads();
    // Phase 2: products p[pr][pc] at global (r0-5+pr, c0-7+pc), 42x44
    for (int l = tid; l < 462; l += 256) {
      int pr = l / 11, pc0 = (l % 11) * 4;
      f32x4 a0 = ld4(&g_s[pr][pc0]);     f32x2 e0 = ld2(&g_s[pr][pc0 + 4]);
      f32x4 a1 = ld4(&g_s[pr + 1][pc0]); f32x2 e1 = ld2(&g_s[pr + 1][pc0 + 4]);
      f32x4 a2 = ld4(&g_s[pr + 2][pc0]); f32x2 e2 = ld2(&g_s[pr + 2][pc0 + 4]);
      float q0[6] = {a0[0], a0[1], a0[2], a0[3], e0[0], e0[1]};
      float q1[6] = {a1[0], a1[1], a1[2], a1[3], e1[0], e1[1]};
      float q2[6] = {a2[0], a2[1], a2[2], a2[3], e2[0], e2[1]};
      f32x4 P0, P1, P2;
#pragma unroll
      for (int j = 0; j < 4; j++) {
        float p0, p1, p2;
        prod3(q0[j], q0[j + 1], q0[j + 2], q1[j], q1[j + 2],
              q2[j], q2[j + 1], q2[j + 2], p0, p1, p2);
        P0[j] = p0; P1[j] = p1; P2[j] = p2;
      }
      *(f32x4*)&p_s[0][pr][pc0] = P0;
      *(f32x4*)&p_s[1][pr][pc0] = P1;
      *(f32x4*)&p_s[2][pr][pc0] = P2;
    }
  } else {
    // Border: scalar gray with replicate clamp
    for (int l = tid; l < 2112; l += 256) {
      int row = l / 48, gc = l % 48;
      int gr = min(max(r0 - 6 + row, 0), H_ - 1);
      int gcl = min(max(c0 - 8 + gc, 0), W_ - 1);
      int o = gr * W_ + gcl;
      g_s[row][gc] = 0.299f * img[o] + 0.587f * img[HW_ + o] + 0.114f * img[2 * HW_ + o];
    }
    __syncthreads();
    // Border: scalar products with reflect mapping (padded coords)
    for (int l = tid; l < 1848; l += 256) {
      int pr = l / 44, pc = l % 44;
      int ar = reflect_i(r0 - 5 + pr, H_);
      int ac = reflect_i(c0 - 7 + pc, W_);
      int rm = max(ar - 1, 0)       - (r0 - 6);
      int rz = ar                   - (r0 - 6);
      int rp = min(ar + 1, H_ - 1)  - (r0 - 6);
      int cm = max(ac - 1, 0)       - (c0 - 8);
      int cz = ac                   - (c0 - 8);
      int cp = min(ac + 1, W_ - 1)  - (c0 - 8);
      float p0, p1, p2;
      prod3(g_s[rm][cm], g_s[rm][cz], g_s[rm][cp],
            g_s[rz][cm],              g_s[rz][cp],
            g_s[rp][cm], g_s[rp][cz], g_s[rp][cp], p0, p1, p2);
      p_s[0][pr][pc] = p0;
      p_s[1][pr][pc] = p1;
      p_s[2][pr][pc] = p2;
    }
  }
  __syncthreads();

  // Phase 3: vertical 7-tap blur, 36 rows x 11 groups (v[vr] ~ row r0-2+vr)
  for (int l = tid; l < 396; l += 256) {
    int vr = l / 11, pc0 = (l % 11) * 4;
    f32x4 s0 = {0.f, 0.f, 0.f, 0.f};
    f32x4 s1 = {0.f, 0.f, 0.f, 0.f};
    f32x4 s2 = {0.f, 0.f, 0.f, 0.f};
#pragma unroll
    for (int k = 0; k < 7; k++) {
      float w = GW[k];
      s0 += w * ld4(&p_s[0][vr + k][pc0]);
      s1 += w * ld4(&p_s[1][vr + k][pc0]);
      s2 += w * ld4(&p_s[2][vr + k][pc0]);
    }
    *(f32x4*)&v_s[0][vr][pc0] = s0;
    *(f32x4*)&v_s[1][vr][pc0] = s1;
    *(f32x4*)&v_s[2][vr][pc0] = s2;
  }
  __syncthreads();

  // Phase 4: horizontal blur + response into r_s[36][36], -inf outside image.
  // (r_s aliases g_s, which is dead after phase 2.)
  for (int l = tid; l < 324; l += 256) {
    int rr = l / 9, rc0 = (l % 9) * 4;
    float wa[3][12];
#pragma unroll
    for (int ch = 0; ch < 3; ch++) {
      f32x4 x = ld4(&v_s[ch][rr][rc0]);
      f32x4 y = ld4(&v_s[ch][rr][rc0 + 4]);
      f32x4 z = ld4(&v_s[ch][rr][rc0 + 8]);
      wa[ch][0] = x[0]; wa[ch][1] = x[1]; wa[ch][2]  = x[2]; wa[ch][3]  = x[3];
      wa[ch][4] = y[0]; wa[ch][5] = y[1]; wa[ch][6]  = y[2]; wa[ch][7]  = y[3];
      wa[ch][8] = z[0]; wa[ch][9] = z[1]; wa[ch][10] = z[2]; wa[ch][11] = z[3];
    }
    int gr = r0 - 2 + rr;
#pragma unroll
    for (int j = 0; j < 4; j++) {
      float b0 = 0.f, b1 = 0.f, b2 = 0.f;
#pragma unroll
      for (int t = 0; t < 7; t++) {
        b0 += GW[t] * wa[0][j + 2 + t];
        b1 += GW[t] * wa[1][j + 2 + t];
        b2 += GW[t] * wa[2][j + 2 + t];
      }
      float tr = b0 + b1;
      float det = b0 * b1 - b2 * b2;
      float rv = 0.5f * (tr - sqrtf(fabsf(tr * tr - 4.f * det) + 1e-12f));
      int gc = c0 - 2 + rc0 + j;
      bool in = ((unsigned)gr < (unsigned)H_) && ((unsigned)gc < (unsigned)W_);
      r_s[rr][rc0 + j] = in ? rv : -INFINITY;
    }
  }
  __syncthreads();

  // Phase 5: 5x5 NMS (x==maxpool keeps value, else 0)
  for (int l = tid; l < 1024; l += 256) {
    int lr = l >> 5, lc = l & 31;
    float v = r_s[lr + 2][lc + 2];
    float m = -INFINITY;
#pragma unroll
    for (int u = 0; u < 5; u++)
#pragma unroll
      for (int w = 0; w < 5; w++) m = fmaxf(m, r_s[lr + u][lc + w]);
    c_s[lr][lc] = (v == m) ? v : 0.f;
  }
  __syncthreads();

  // Phase 6: per-8x8-block max into deterministic cand slot (min-idx tiebreak)
  if (tid < 16) {
    int sr = (tid >> 2) << 3, sc_ = (tid & 3) << 3;
    float m = 0.f;
    int mi = INT_MAX;
#pragma unroll
    for (int u = 0; u < 8; u++)
      for (int w = 0; w < 8; w++) {
        float v = c_s[sr + u][sc_ + w];
        if (v > m) { m = v; mi = (r0 + sr + u) * W_ + (c0 + sc_ + w); }
      }
    int subg = ((r0 + sr) >> 3) * 64 + ((c0 + sc_) >> 3);
    bool pos = (m > 0.f);
    cand_val[b * CAP_ + subg] = pos ? m : -INFINITY;
    cand_idx[b * CAP_ + subg] = pos ? mi : INT_MAX;
  }

  // Phase 7: BCE base chunk reduce -> part[bid]
  float s = fmaxf(log1pf(-sc[0]), -100.f) + fmaxf(log1pf(-sc[1]), -100.f) +
            fmaxf(log1pf(-sc[2]), -100.f) + fmaxf(log1pf(-sc[3]), -100.f);
  for (int off = 32; off > 0; off >>= 1) s += __shfl_down(s, off);
  if ((tid & 63) == 0) wsum[tid >> 6] = s;
  __syncthreads();
  if (tid == 0) {
    double t = (double)wsum[0] + (double)wsum[1] + (double)wsum[2] + (double)wsum[3];
    part[bid] = t;  // deterministic slot, overwritten every call
  }
}

// K2: per-image top-500 via MSB-first RADIX SELECT (no sort). Items live in
// registers (4/thread). 4 passes x 8 bits: LDS histogram, then WAVE-0-ONLY
// parallel suffix-scan over the 256 bins (4 bins/lane + 6-step shfl_down).
// Finds the 500th-largest key T and `need` = slots left for key==T (idx asc,
// matching jax.lax.top_k tie order). Second nms2d is a provable no-op (equal
// values survive x==maxpool), so every selected positive item is a corner:
// add its BCE swap term (log p - log1p(-p)) to part[NTILE_+b].
__global__ __launch_bounds__(1024) void k_select(const float* __restrict__ cand_val,
                                                 const int* __restrict__ cand_idx,
                                                 const float* __restrict__ scores,
                                                 double* __restrict__ part) {
  int b = blockIdx.x;
  __shared__ unsigned hist[256];
  __shared__ unsigned s_prefix;
  __shared__ int s_rank;
  __shared__ int eq_idx[1024];
  __shared__ int eq_cnt;
  __shared__ float wsum[16];
  int tid = threadIdx.x;

  unsigned key[4];
  int idx[4];
#pragma unroll
  for (int q = 0; q < 4; q++) {
    int l = tid + q * 1024;
    float v = cand_val[b * CAP_ + l];
    idx[q] = cand_idx[b * CAP_ + l];
    unsigned u = __float_as_uint(v);
    key[q] = (u & 0x80000000u) ? ~u : (u | 0x80000000u);  // order-preserving
  }
  if (tid == 0) { s_rank = NSEL_; s_prefix = 0; eq_cnt = 0; }

  for (int pass = 0; pass < 4; pass++) {
    int shift = 24 - 8 * pass;
    if (tid < 256) hist[tid] = 0;
    __syncthreads();
    unsigned pref = s_prefix;   // read-before-write: writes after next barrier
    int rank = s_rank;
#pragma unroll
    for (int q = 0; q < 4; q++) {
      bool match = (pass == 0) || ((key[q] >> (shift + 8)) == pref);
      if (match) atomicAdd(&hist[(key[q] >> shift) & 255u], 1u);
    }
    __syncthreads();
    if (tid < 64) {
      unsigned h0 = hist[tid * 4 + 0], h1 = hist[tid * 4 + 1];
      unsigned h2 = hist[tid * 4 + 2], h3 = hist[tid * 4 + 3];
      unsigned tot = h0 + h1 + h2 + h3;
      unsigned suf = tot;  // suffix sum over lanes >= tid
#pragma unroll
      for (int off = 1; off < 64; off <<= 1) {
        unsigned o = __shfl_down(suf, off);
        if (tid + off < 64) suf += o;
      }
      unsigned above3 = suf - tot;
      unsigned above2 = above3 + h3;
      unsigned above1 = above2 + h2;
      unsigned above0 = above1 + h1;
      unsigned r = (unsigned)rank;
      if (above0 < r && r <= above0 + h0) { s_rank = (int)(r - above0); s_prefix = (pref << 8) | (unsigned)(tid * 4 + 0); }
      if (above1 < r && r <= above1 + h1) { s_rank = (int)(r - above1); s_prefix = (pref << 8) | (unsigned)(tid * 4 + 1); }
      if (above2 < r && r <= above2 + h2) { s_rank = (int)(r - above2); s_prefix = (pref << 8) | (unsigned)(tid * 4 + 2); }
      if (above3 < r && r <= above3 + h3) { s_rank = (int)(r - above3); s_prefix = (pref << 8) | (unsigned)(tid * 4 + 3); }
    }
    __syncthreads();
  }
  unsigned T = s_prefix;
  int need = s_rank;

#pragma unroll
  for (int q = 0; q < 4; q++) {
    if (key[q] == T) {
      int pos = atomicAdd(&eq_cnt, 1);
      if (pos < 1024) eq_idx[pos] = idx[q];
    }
  }
  __syncthreads();
  int E = min(eq_cnt, 1024);

  const unsigned KPOS = 0x80000000u;  // key of +0.0; corners need value > 0
  float term = 0.f;
#pragma unroll
  for (int q = 0; q < 4; q++) {
    bool corner = false;
    if (key[q] > KPOS) {
      if (key[q] > T) {
        corner = true;
      } else if (key[q] == T) {
        int r = 0;
        for (int j = 0; j < E; j++) r += (eq_idx[j] < idx[q]);
        corner = (r < need);
      }
    }
    if (corner) {
      float p = scores[(size_t)b * HW_ + idx[q]];
      term += fmaxf(logf(p), -100.f) - fmaxf(log1pf(-p), -100.f);
    }
  }
  for (int off = 32; off > 0; off >>= 1) term += __shfl_down(term, off);
  if ((tid & 63) == 0) wsum[tid >> 6] = term;
  __syncthreads();
  if (tid == 0) {
    double s = 0.0;
    for (int i = 0; i < 16; i++) s += (double)wsum[i];
    part[NTILE_ + b] = s;  // deterministic slot, overwritten every call
  }
}

// K3: reduce the NPART_ partial doubles -> loss. One block, 256 threads.
__global__ __launch_bounds__(256) void k_final(const double* __restrict__ part,
                                               float* __restrict__ out) {
  __shared__ double wsum[4];
  int tid = threadIdx.x;
  double s = 0.0;
  for (int i = tid; i < NPART_; i += 256) s += part[i];
  for (int off = 32; off > 0; off >>= 1) s += __shfl_down(s, off);
  if ((tid & 63) == 0) wsum[tid >> 6] = s;
  __syncthreads();
  if (tid == 0) {
    double t = wsum[0] + wsum[1] + wsum[2] + wsum[3];
    out[0] = (float)(-t / (double)((size_t)B_ * HW_));
  }
}

}  // namespace

extern "C" void kernel_launch(void* const* d_in, const int* in_sizes, int n_in,
                              void* d_out, int out_size, void* d_ws, size_t ws_size,
                              hipStream_t stream) {
  const float* scores = (const float*)d_in[0];
  const float* imgs = (const float*)d_in[1];
  float* out = (float*)d_out;

  char* ws = (char*)d_ws;
  double* part = (double*)ws;                      // NPART_ doubles (32,896 B)
  float* cand_val = (float*)(ws + 33024);          // 16*4096 f32
  int* cand_idx = (int*)(ws + 33024 + 262144);     // 16*4096 i32

  k_main<<<NTILE_, 256, 0, stream>>>(imgs, scores, cand_val, cand_idx, part);
  k_select<<<B_, 1024, 0, stream>>>(cand_val, cand_idx, scores, part);
  k_final<<<1, 256, 0, stream>>>(part, out);
}

// Round 9
// 78.998 us; speedup vs baseline: 1.1549x; 1.1549x over previous
//
#include <hip/hip_runtime.h>
#include <math.h>
#include <limits.h>

namespace {

constexpr int B_ = 16;
constexpr int H_ = 512;
constexpr int W_ = 512;
constexpr int HW_ = H_ * W_;
constexpr int CAP_ = 4096;           // one slot per 8x8 sub-block per image
constexpr int NSEL_ = 500;
constexpr int NTILE_ = B_ * 256;     // 4096 tile blocks
constexpr int NPART_ = NTILE_ + B_;  // partial-sum slots (k_nms chunks + k_select)

typedef float f32x4 __attribute__((ext_vector_type(4)));
typedef float f32x2 __attribute__((ext_vector_type(2)));

__device__ inline f32x4 ld4(const float* p) { return *(const f32x4*)p; }
__device__ inline f32x2 ld2(const float* p) { return *(const f32x2*)p; }

// 7-tap gaussian, sigma=1, normalized (matches reference's np.exp/sum)
__device__ constexpr float GW[7] = {
    0.004433048175243746f, 0.05400558262251428f, 0.24203622937611957f,
    0.3990502796522496f,  0.24203622937611957f, 0.05400558262251428f,
    0.004433048175243746f};

__device__ inline int reflect_i(int i, int n) {
  // jnp.pad mode='reflect': -1 -> 1, n -> n-2
  return i < 0 ? -i : (i > n - 1 ? 2 * (n - 1) - i : i);
}

// K1: imgs -> GFTT response map. One block = one 32x32 output tile.
// Interior tiles (bx,by in [1,14]): float4 paths, no clamps.
// LDS rows padded to stride 40 floats (160B) for aligned b128 ops.
// (Round-7 proven version, absmax 0.0 — unchanged.)
__global__ __launch_bounds__(256) void k_resp(const float* __restrict__ imgs,
                                              float* __restrict__ resp) {
  int bid = blockIdx.x;
  int bx = bid & 15, by = (bid >> 4) & 15, b = bid >> 8;
  int r0 = by * 32, c0 = bx * 32;
  __shared__ __align__(16) float g_s[40][40];
  __shared__ __align__(16) float p_s[3][38][40];
  __shared__ __align__(16) float v_s[3][32][40];
  int tid = threadIdx.x;
  const float* img = imgs + (size_t)b * 3 * HW_;
  bool interior = (bx >= 1 && bx <= 14 && by >= 1 && by <= 14);

  if (interior) {
    // Phase 1: grayscale, 40 rows x 10 float4 cols, all in-bounds & aligned
    for (int l = tid; l < 400; l += 256) {
      int row = l / 10, c4 = (l % 10) * 4;
      int o = (r0 - 4 + row) * W_ + (c0 - 4 + c4);
      f32x4 R = ld4(&img[o]);
      f32x4 G = ld4(&img[HW_ + o]);
      f32x4 Bl = ld4(&img[2 * HW_ + o]);
      f32x4 gray = 0.299f * R + 0.587f * G + 0.114f * Bl;
      *(f32x4*)&g_s[row][c4] = gray;
    }
    __syncthreads();
    // Phase 2: gradient products, 38 rows x 10 groups of 4 cols.
    for (int l = tid; l < 380; l += 256) {
      int pr = l / 10, c = (l % 10) * 4;
      f32x4 a0 = ld4(&g_s[pr][c]);     f32x2 e0 = ld2(&g_s[pr][c + 4]);
      f32x4 a1 = ld4(&g_s[pr + 1][c]); f32x2 e1 = ld2(&g_s[pr + 1][c + 4]);
      f32x4 a2 = ld4(&g_s[pr + 2][c]); f32x2 e2 = ld2(&g_s[pr + 2][c + 4]);
      float q0[6] = {a0[0], a0[1], a0[2], a0[3], e0[0], e0[1]};
      float q1[6] = {a1[0], a1[1], a1[2], a1[3], e1[0], e1[1]};
      float q2[6] = {a2[0], a2[1], a2[2], a2[3], e2[0], e2[1]};
      f32x4 P0, P1, P2;
#pragma unroll
      for (int j = 0; j < 4; j++) {
        float dxr = (q0[j + 2] - q0[j]) + 2.f * (q1[j + 2] - q1[j]) + (q2[j + 2] - q2[j]);
        float dyr = (q2[j] - q0[j]) + 2.f * (q2[j + 1] - q0[j + 1]) + (q2[j + 2] - q0[j + 2]);
        const float cc = 1.f / 64.f;  // sobel /8 twice, folded
        float t = dxr * cc, u = dyr * cc;
        P0[j] = t * dxr;
        P1[j] = u * dyr;
        P2[j] = t * dyr;
      }
      *(f32x4*)&p_s[0][pr][c] = P0;
      *(f32x4*)&p_s[1][pr][c] = P1;
      *(f32x4*)&p_s[2][pr][c] = P2;
    }
  } else {
    // border tiles: scalar path with replicate clamp + reflect (proven)
    for (int l = tid; l < 40 * 40; l += 256) {
      int lr = l / 40, lc = l % 40;
      int gr = min(max(r0 - 4 + lr, 0), H_ - 1);
      int gc = min(max(c0 - 4 + lc, 0), W_ - 1);
      int o = gr * W_ + gc;
      g_s[lr][lc] = 0.299f * img[o] + 0.587f * img[HW_ + o] + 0.114f * img[2 * HW_ + o];
    }
    __syncthreads();
    for (int l = tid; l < 38 * 38; l += 256) {
      int lr = l / 38, lc = l % 38;
      int ar = reflect_i(r0 - 3 + lr, H_);
      int ac = reflect_i(c0 - 3 + lc, W_);
      int rm = max(ar - 1, 0)      - (r0 - 4);
      int rz = ar                  - (r0 - 4);
      int rp = min(ar + 1, H_ - 1) - (r0 - 4);
      int cm = max(ac - 1, 0)      - (c0 - 4);
      int cz = ac                  - (c0 - 4);
      int cp = min(ac + 1, W_ - 1) - (c0 - 4);
      float gnw = g_s[rm][cm], gn = g_s[rm][cz], gne = g_s[rm][cp];
      float gw_ = g_s[rz][cm],                   ge  = g_s[rz][cp];
      float gsw = g_s[rp][cm], gs = g_s[rp][cz], gse = g_s[rp][cp];
      float dx = ((gne - gnw) + 2.f * (ge - gw_) + (gse - gsw)) * 0.125f;
      float dy = ((gsw - gnw) + 2.f * (gs - gn) + (gse - gne)) * 0.125f;
      p_s[0][lr][lc] = dx * dx;
      p_s[1][lr][lc] = dy * dy;
      p_s[2][lr][lc] = dx * dy;
    }
  }
  __syncthreads();

  // Phase 3: vertical 7-tap blur, 32 rows x 10 groups, b128 taps.
  for (int l = tid; l < 320; l += 256) {
    int vr = l / 10, c = (l % 10) * 4;
    f32x4 s0 = {0.f, 0.f, 0.f, 0.f};
    f32x4 s1 = {0.f, 0.f, 0.f, 0.f};
    f32x4 s2 = {0.f, 0.f, 0.f, 0.f};
#pragma unroll
    for (int k = 0; k < 7; k++) {
      float w = GW[k];
      s0 += w * ld4(&p_s[0][vr + k][c]);
      s1 += w * ld4(&p_s[1][vr + k][c]);
      s2 += w * ld4(&p_s[2][vr + k][c]);
    }
    *(f32x4*)&v_s[0][vr][c] = s0;
    *(f32x4*)&v_s[1][vr][c] = s1;
    *(f32x4*)&v_s[2][vr][c] = s2;
  }
  __syncthreads();

  // Phase 4: horizontal blur + response, 32 rows x 8 groups = 1 per thread.
  {
    int r = tid >> 3;
    int c = (tid & 7) << 2;
    float wa[3][10];
#pragma unroll
    for (int ch = 0; ch < 3; ch++) {
      f32x4 x = ld4(&v_s[ch][r][c]);
      f32x4 y = ld4(&v_s[ch][r][c + 4]);
      f32x2 z = ld2(&v_s[ch][r][c + 8]);
      wa[ch][0] = x[0]; wa[ch][1] = x[1]; wa[ch][2] = x[2]; wa[ch][3] = x[3];
      wa[ch][4] = y[0]; wa[ch][5] = y[1]; wa[ch][6] = y[2]; wa[ch][7] = y[3];
      wa[ch][8] = z[0]; wa[ch][9] = z[1];
    }
    f32x4 outv;
#pragma unroll
    for (int j = 0; j < 4; j++) {
      float b0 = 0.f, b1 = 0.f, b2 = 0.f;
#pragma unroll
      for (int t = 0; t < 7; t++) {
        b0 += GW[t] * wa[0][j + t];
        b1 += GW[t] * wa[1][j + t];
        b2 += GW[t] * wa[2][j + t];
      }
      float tr = b0 + b1;
      float det = b0 * b1 - b2 * b2;
      outv[j] = 0.5f * (tr - sqrtf(fabsf(tr * tr - 4.f * det) + 1e-12f));
    }
    *(f32x4*)&resp[((size_t)b * H_ + (r0 + r)) * W_ + (c0 + c)] = outv;
  }
}

// K2: 5x5 NMS via SEPARABLE max (row-max then col-max) + per-8x8-block max
// into deterministic cand slot. Also absorbs the BCE base sum for a
// 1024-float chunk of scores (load issued first, reduced last -> hidden).
__global__ __launch_bounds__(256) void k_nms(const float* __restrict__ resp,
                                             const float* __restrict__ scores,
                                             float* __restrict__ cand_val,
                                             int* __restrict__ cand_idx,
                                             double* __restrict__ part) {
  int bid = blockIdx.x;
  int bx = bid & 15, by = (bid >> 4) & 15, b = bid >> 8;
  int r0 = by * 32, c0 = bx * 32;
  __shared__ __align__(16) float r_s[36][40];
  __shared__ float rm_s[36][32];
  __shared__ float c_s[32][32];
  __shared__ float wsum[4];
  int tid = threadIdx.x;

  // BCE base chunk: issue load now, consume at the end.
  f32x4 sc = ld4(scores + (size_t)bid * 1024 + tid * 4);

  const float* rb = resp + (size_t)b * HW_;
  bool interior = (bx >= 1 && bx <= 14 && by >= 1 && by <= 14);
  if (interior) {
    // rows r0-2..r0+33, cols c0-4..c0+35 (aligned f32x4), 36 x 10 groups
    for (int l = tid; l < 360; l += 256) {
      int lr = l / 10, c4 = (l % 10) * 4;
      *(f32x4*)&r_s[lr][c4] = ld4(&rb[(r0 - 2 + lr) * W_ + (c0 - 4 + c4)]);
    }
  } else {
    for (int l = tid; l < 36 * 40; l += 256) {
      int lr = l / 40, lc = l % 40;
      int gr = r0 - 2 + lr, gc = c0 - 4 + lc;
      float v = -INFINITY;
      if (gr >= 0 && gr < H_ && gc >= 0 && gc < W_) v = rb[gr * W_ + gc];
      r_s[lr][lc] = v;
    }
  }
  __syncthreads();

  // row-max: rm[r][c] = max over r_s[r][c+2..c+6]  (center col = c+4)
  for (int l = tid; l < 1152; l += 256) {
    int r = l >> 5, c = l & 31;
    float m = fmaxf(fmaxf(fmaxf(r_s[r][c + 2], r_s[r][c + 3]),
                          fmaxf(r_s[r][c + 4], r_s[r][c + 5])),
                    r_s[r][c + 6]);
    rm_s[r][c] = m;
  }
  __syncthreads();

  // col-max + keep-if-equal (x == 5x5 maxpool)
  for (int l = tid; l < 1024; l += 256) {
    int r = l >> 5, c = l & 31;
    float m = fmaxf(fmaxf(fmaxf(rm_s[r][c], rm_s[r + 1][c]),
                          fmaxf(rm_s[r + 2][c], rm_s[r + 3][c])),
                    rm_s[r + 4][c]);
    float v = r_s[r + 2][c + 4];
    c_s[r][c] = (v == m) ? v : 0.f;
  }
  __syncthreads();

  // per-8x8-block max into deterministic cand slot (min-idx tiebreak)
  if (tid < 16) {
    int sr = (tid >> 2) << 3, sc_ = (tid & 3) << 3;
    float m = 0.f;
    int mi = INT_MAX;
#pragma unroll
    for (int u = 0; u < 8; u++)
      for (int w = 0; w < 8; w++) {
        float v = c_s[sr + u][sc_ + w];
        if (v > m) { m = v; mi = (r0 + sr + u) * W_ + (c0 + sc_ + w); }
      }
    int subg = ((r0 + sr) >> 3) * 64 + ((c0 + sc_) >> 3);
    bool pos = (m > 0.f);
    cand_val[b * CAP_ + subg] = pos ? m : -INFINITY;
    cand_idx[b * CAP_ + subg] = pos ? mi : INT_MAX;
  }

  // BCE base chunk reduce -> part[bid]
  float s = fmaxf(log1pf(-sc[0]), -100.f) + fmaxf(log1pf(-sc[1]), -100.f) +
            fmaxf(log1pf(-sc[2]), -100.f) + fmaxf(log1pf(-sc[3]), -100.f);
  for (int off = 32; off > 0; off >>= 1) s += __shfl_down(s, off);
  if ((tid & 63) == 0) wsum[tid >> 6] = s;
  __syncthreads();
  if (tid == 0) {
    double t = (double)wsum[0] + (double)wsum[1] + (double)wsum[2] + (double)wsum[3];
    part[bid] = t;  // deterministic slot, overwritten every call
  }
}

// K3: per-image top-500 via MSB-first RADIX SELECT (no sort). Items live in
// registers (4/thread). 4 passes x 8 bits: LDS histogram, then WAVE-0-ONLY
// parallel suffix-scan over the 256 bins (4 bins/lane + 6-step shfl_down).
// Finds the 500th-largest key T and `need` = slots left for key==T (idx asc,
// matching jax.lax.top_k tie order). Second nms2d is a provable no-op (equal
// values survive x==maxpool), so every selected positive item is a corner:
// add its BCE swap term (log p - log1p(-p)) to part[NTILE_+b].
__global__ __launch_bounds__(1024) void k_select(const float* __restrict__ cand_val,
                                                 const int* __restrict__ cand_idx,
                                                 const float* __restrict__ scores,
                                                 double* __restrict__ part) {
  int b = blockIdx.x;
  __shared__ unsigned hist[256];
  __shared__ unsigned s_prefix;
  __shared__ int s_rank;
  __shared__ int eq_idx[1024];
  __shared__ int eq_cnt;
  __shared__ float wsum[16];
  int tid = threadIdx.x;

  unsigned key[4];
  int idx[4];
#pragma unroll
  for (int q = 0; q < 4; q++) {
    int l = tid + q * 1024;
    float v = cand_val[b * CAP_ + l];
    idx[q] = cand_idx[b * CAP_ + l];
    unsigned u = __float_as_uint(v);
    key[q] = (u & 0x80000000u) ? ~u : (u | 0x80000000u);  // order-preserving
  }
  if (tid == 0) { s_rank = NSEL_; s_prefix = 0; eq_cnt = 0; }

  for (int pass = 0; pass < 4; pass++) {
    int shift = 24 - 8 * pass;
    if (tid < 256) hist[tid] = 0;
    __syncthreads();
    unsigned pref = s_prefix;   // read-before-write: writes after next barrier
    int rank = s_rank;
#pragma unroll
    for (int q = 0; q < 4; q++) {
      bool match = (pass == 0) || ((key[q] >> (shift + 8)) == pref);
      if (match) atomicAdd(&hist[(key[q] >> shift) & 255u], 1u);
    }
    __syncthreads();
    if (tid < 64) {
      unsigned h0 = hist[tid * 4 + 0], h1 = hist[tid * 4 + 1];
      unsigned h2 = hist[tid * 4 + 2], h3 = hist[tid * 4 + 3];
      unsigned tot = h0 + h1 + h2 + h3;
      unsigned suf = tot;  // suffix sum over lanes >= tid
#pragma unroll
      for (int off = 1; off < 64; off <<= 1) {
        unsigned o = __shfl_down(suf, off);
        if (tid + off < 64) suf += o;
      }
      unsigned above3 = suf - tot;
      unsigned above2 = above3 + h3;
      unsigned above1 = above2 + h2;
      unsigned above0 = above1 + h1;
      unsigned r = (unsigned)rank;
      if (above0 < r && r <= above0 + h0) { s_rank = (int)(r - above0); s_prefix = (pref << 8) | (unsigned)(tid * 4 + 0); }
      if (above1 < r && r <= above1 + h1) { s_rank = (int)(r - above1); s_prefix = (pref << 8) | (unsigned)(tid * 4 + 1); }
      if (above2 < r && r <= above2 + h2) { s_rank = (int)(r - above2); s_prefix = (pref << 8) | (unsigned)(tid * 4 + 2); }
      if (above3 < r && r <= above3 + h3) { s_rank = (int)(r - above3); s_prefix = (pref << 8) | (unsigned)(tid * 4 + 3); }
    }
    __syncthreads();
  }
  unsigned T = s_prefix;
  int need = s_rank;

#pragma unroll
  for (int q = 0; q < 4; q++) {
    if (key[q] == T) {
      int pos = atomicAdd(&eq_cnt, 1);
      if (pos < 1024) eq_idx[pos] = idx[q];
    }
  }
  __syncthreads();
  int E = min(eq_cnt, 1024);

  const unsigned KPOS = 0x80000000u;  // key of +0.0; corners need value > 0
  float term = 0.f;
#pragma unroll
  for (int q = 0; q < 4; q++) {
    bool corner = false;
    if (key[q] > KPOS) {
      if (key[q] > T) {
        corner = true;
      } else if (key[q] == T) {
        int r = 0;
        for (int j = 0; j < E; j++) r += (eq_idx[j] < idx[q]);
        corner = (r < need);
      }
    }
    if (corner) {
      float p = scores[(size_t)b * HW_ + idx[q]];
      term += fmaxf(logf(p), -100.f) - fmaxf(log1pf(-p), -100.f);
    }
  }
  for (int off = 32; off > 0; off >>= 1) term += __shfl_down(term, off);
  if ((tid & 63) == 0) wsum[tid >> 6] = term;
  __syncthreads();
  if (tid == 0) {
    double s = 0.0;
    for (int i = 0; i < 16; i++) s += (double)wsum[i];
    part[NTILE_ + b] = s;  // deterministic slot, overwritten every call
  }
}

// K4: reduce the NPART_ partial doubles -> loss. One block, 256 threads.
__global__ __launch_bounds__(256) void k_final(const double* __restrict__ part,
                                               float* __restrict__ out) {
  __shared__ double wsum[4];
  int tid = threadIdx.x;
  double s = 0.0;
  for (int i = tid; i < NPART_; i += 256) s += part[i];
  for (int off = 32; off > 0; off >>= 1) s += __shfl_down(s, off);
  if ((tid & 63) == 0) wsum[tid >> 6] = s;
  __syncthreads();
  if (tid == 0) {
    double t = wsum[0] + wsum[1] + wsum[2] + wsum[3];
    out[0] = (float)(-t / (double)((size_t)B_ * HW_));
  }
}

}  // namespace

extern "C" void kernel_launch(void* const* d_in, const int* in_sizes, int n_in,
                              void* d_out, int out_size, void* d_ws, size_t ws_size,
                              hipStream_t stream) {
  const float* scores = (const float*)d_in[0];
  const float* imgs = (const float*)d_in[1];
  float* out = (float*)d_out;

  char* ws = (char*)d_ws;
  double* part = (double*)ws;                          // NPART_ doubles (32,896 B)
  float* resp = (float*)(ws + 33024);                  // 16 MB, 16B-aligned
  float* cand_val = resp + (size_t)B_ * HW_;           // 16*4096 f32
  int* cand_idx = (int*)(cand_val + B_ * CAP_);        // 16*4096 i32

  k_resp<<<NTILE_, 256, 0, stream>>>(imgs, resp);
  k_nms<<<NTILE_, 256, 0, stream>>>(resp, scores, cand_val, cand_idx, part);
  k_select<<<B_, 1024, 0, stream>>>(cand_val, cand_idx, scores, part);
  k_final<<<1, 256, 0, stream>>>(part, out);
}

// Round 10
// 75.007 us; speedup vs baseline: 1.2163x; 1.0532x over previous
//
#include <hip/hip_runtime.h>
#include <math.h>
#include <limits.h>

namespace {

constexpr int B_ = 16;
constexpr int H_ = 512;
constexpr int W_ = 512;
constexpr int HW_ = H_ * W_;
constexpr int CAP_ = 4096;           // one slot per 8x8 sub-block per image
constexpr int NSEL_ = 500;
constexpr int NTILE_ = B_ * 256;     // 4096 tile blocks
constexpr int NPART_ = NTILE_ + B_;  // partial-sum slots (k_nms chunks + k_select)

typedef float f32x4 __attribute__((ext_vector_type(4)));
typedef float f32x2 __attribute__((ext_vector_type(2)));

__device__ inline f32x4 ld4(const float* p) { return *(const f32x4*)p; }
__device__ inline f32x2 ld2(const float* p) { return *(const f32x2*)p; }

// 7-tap gaussian, sigma=1, normalized (matches reference's np.exp/sum)
__device__ constexpr float GW[7] = {
    0.004433048175243746f, 0.05400558262251428f, 0.24203622937611957f,
    0.3990502796522496f,  0.24203622937611957f, 0.05400558262251428f,
    0.004433048175243746f};

__device__ inline int reflect_i(int i, int n) {
  // jnp.pad mode='reflect': -1 -> 1, n -> n-2
  return i < 0 ? -i : (i > n - 1 ? 2 * (n - 1) - i : i);
}

// K1: imgs -> GFTT response map. One block = one 32x32 output tile.
// Interior tiles (bx,by in [1,14]): float4 paths, no clamps.
// LDS rows padded to stride 40 floats (160B) for aligned b128 ops.
// P3 uses a 10-row register sliding window: 4 output rows per item.
// Block 0 also resets the k_select done-counter (used 2 kernels later).
__global__ __launch_bounds__(256) void k_resp(const float* __restrict__ imgs,
                                              float* __restrict__ resp,
                                              int* __restrict__ done) {
  int bid = blockIdx.x;
  int bx = bid & 15, by = (bid >> 4) & 15, b = bid >> 8;
  int r0 = by * 32, c0 = bx * 32;
  __shared__ __align__(16) float g_s[40][40];
  __shared__ __align__(16) float p_s[3][38][40];
  __shared__ __align__(16) float v_s[3][32][40];
  int tid = threadIdx.x;
  const float* img = imgs + (size_t)b * 3 * HW_;
  bool interior = (bx >= 1 && bx <= 14 && by >= 1 && by <= 14);

  if (bid == 0 && tid == 0) done[0] = 0;  // reset for k_select's last-block fuse

  if (interior) {
    // Phase 1: grayscale, 40 rows x 10 float4 cols, all in-bounds & aligned
    for (int l = tid; l < 400; l += 256) {
      int row = l / 10, c4 = (l % 10) * 4;
      int o = (r0 - 4 + row) * W_ + (c0 - 4 + c4);
      f32x4 R = ld4(&img[o]);
      f32x4 G = ld4(&img[HW_ + o]);
      f32x4 Bl = ld4(&img[2 * HW_ + o]);
      f32x4 gray = 0.299f * R + 0.587f * G + 0.114f * Bl;
      *(f32x4*)&g_s[row][c4] = gray;
    }
    __syncthreads();
    // Phase 2: gradient products, 38 rows x 10 groups of 4 cols.
    for (int l = tid; l < 380; l += 256) {
      int pr = l / 10, c = (l % 10) * 4;
      f32x4 a0 = ld4(&g_s[pr][c]);     f32x2 e0 = ld2(&g_s[pr][c + 4]);
      f32x4 a1 = ld4(&g_s[pr + 1][c]); f32x2 e1 = ld2(&g_s[pr + 1][c + 4]);
      f32x4 a2 = ld4(&g_s[pr + 2][c]); f32x2 e2 = ld2(&g_s[pr + 2][c + 4]);
      float q0[6] = {a0[0], a0[1], a0[2], a0[3], e0[0], e0[1]};
      float q1[6] = {a1[0], a1[1], a1[2], a1[3], e1[0], e1[1]};
      float q2[6] = {a2[0], a2[1], a2[2], a2[3], e2[0], e2[1]};
      f32x4 P0, P1, P2;
#pragma unroll
      for (int j = 0; j < 4; j++) {
        float dxr = (q0[j + 2] - q0[j]) + 2.f * (q1[j + 2] - q1[j]) + (q2[j + 2] - q2[j]);
        float dyr = (q2[j] - q0[j]) + 2.f * (q2[j + 1] - q0[j + 1]) + (q2[j + 2] - q0[j + 2]);
        const float cc = 1.f / 64.f;  // sobel /8 twice, folded
        float t = dxr * cc, u = dyr * cc;
        P0[j] = t * dxr;
        P1[j] = u * dyr;
        P2[j] = t * dyr;
      }
      *(f32x4*)&p_s[0][pr][c] = P0;
      *(f32x4*)&p_s[1][pr][c] = P1;
      *(f32x4*)&p_s[2][pr][c] = P2;
    }
  } else {
    // border tiles: scalar path with replicate clamp + reflect (proven)
    for (int l = tid; l < 40 * 40; l += 256) {
      int lr = l / 40, lc = l % 40;
      int gr = min(max(r0 - 4 + lr, 0), H_ - 1);
      int gc = min(max(c0 - 4 + lc, 0), W_ - 1);
      int o = gr * W_ + gc;
      g_s[lr][lc] = 0.299f * img[o] + 0.587f * img[HW_ + o] + 0.114f * img[2 * HW_ + o];
    }
    __syncthreads();
    for (int l = tid; l < 38 * 38; l += 256) {
      int lr = l / 38, lc = l % 38;
      int ar = reflect_i(r0 - 3 + lr, H_);
      int ac = reflect_i(c0 - 3 + lc, W_);
      int rm = max(ar - 1, 0)      - (r0 - 4);
      int rz = ar                  - (r0 - 4);
      int rp = min(ar + 1, H_ - 1) - (r0 - 4);
      int cm = max(ac - 1, 0)      - (c0 - 4);
      int cz = ac                  - (c0 - 4);
      int cp = min(ac + 1, W_ - 1) - (c0 - 4);
      float gnw = g_s[rm][cm], gn = g_s[rm][cz], gne = g_s[rm][cp];
      float gw_ = g_s[rz][cm],                   ge  = g_s[rz][cp];
      float gsw = g_s[rp][cm], gs = g_s[rp][cz], gse = g_s[rp][cp];
      float dx = ((gne - gnw) + 2.f * (ge - gw_) + (gse - gsw)) * 0.125f;
      float dy = ((gsw - gnw) + 2.f * (gs - gn) + (gse - gne)) * 0.125f;
      p_s[0][lr][lc] = dx * dx;
      p_s[1][lr][lc] = dy * dy;
      p_s[2][lr][lc] = dx * dy;
    }
  }
  __syncthreads();

  // Phase 3: vertical 7-tap blur via register sliding window.
  // item = (ch, row-quad, col-group): 3*8*10 = 240 items, 1 per thread.
  // Reads 10 rows once (10 b128), emits 4 output rows (7-tap windows).
  if (tid < 240) {
    int ch = tid / 80;
    int rq = (tid / 10) % 8;
    int cg = tid % 10;
    int c = cg * 4;
    int vr0 = rq * 4;
    f32x4 w[10];
#pragma unroll
    for (int k = 0; k < 10; k++) w[k] = ld4(&p_s[ch][vr0 + k][c]);
#pragma unroll
    for (int j = 0; j < 4; j++) {
      f32x4 s = {0.f, 0.f, 0.f, 0.f};
#pragma unroll
      for (int t = 0; t < 7; t++) s += GW[t] * w[j + t];
      *(f32x4*)&v_s[ch][vr0 + j][c] = s;
    }
  }
  __syncthreads();

  // Phase 4: horizontal blur + response, 32 rows x 8 groups = 1 per thread.
  {
    int r = tid >> 3;
    int c = (tid & 7) << 2;
    float wa[3][10];
#pragma unroll
    for (int ch = 0; ch < 3; ch++) {
      f32x4 x = ld4(&v_s[ch][r][c]);
      f32x4 y = ld4(&v_s[ch][r][c + 4]);
      f32x2 z = ld2(&v_s[ch][r][c + 8]);
      wa[ch][0] = x[0]; wa[ch][1] = x[1]; wa[ch][2] = x[2]; wa[ch][3] = x[3];
      wa[ch][4] = y[0]; wa[ch][5] = y[1]; wa[ch][6] = y[2]; wa[ch][7] = y[3];
      wa[ch][8] = z[0]; wa[ch][9] = z[1];
    }
    f32x4 outv;
#pragma unroll
    for (int j = 0; j < 4; j++) {
      float b0 = 0.f, b1 = 0.f, b2 = 0.f;
#pragma unroll
      for (int t = 0; t < 7; t++) {
        b0 += GW[t] * wa[0][j + t];
        b1 += GW[t] * wa[1][j + t];
        b2 += GW[t] * wa[2][j + t];
      }
      float tr = b0 + b1;
      float det = b0 * b1 - b2 * b2;
      outv[j] = 0.5f * (tr - sqrtf(fabsf(tr * tr - 4.f * det) + 1e-12f));
    }
    *(f32x4*)&resp[((size_t)b * H_ + (r0 + r)) * W_ + (c0 + c)] = outv;
  }
}

// K2: 5x5 NMS via SEPARABLE max (row-max then col-max) + per-8x8-block max
// into deterministic cand slot. Also absorbs the BCE base sum for a
// 1024-float chunk of scores (load issued first, reduced last -> hidden).
__global__ __launch_bounds__(256) void k_nms(const float* __restrict__ resp,
                                             const float* __restrict__ scores,
                                             float* __restrict__ cand_val,
                                             int* __restrict__ cand_idx,
                                             double* __restrict__ part) {
  int bid = blockIdx.x;
  int bx = bid & 15, by = (bid >> 4) & 15, b = bid >> 8;
  int r0 = by * 32, c0 = bx * 32;
  __shared__ __align__(16) float r_s[36][40];
  __shared__ float rm_s[36][32];
  __shared__ float c_s[32][32];
  __shared__ float wsum[4];
  int tid = threadIdx.x;

  // BCE base chunk: issue load now, consume at the end.
  f32x4 sc = ld4(scores + (size_t)bid * 1024 + tid * 4);

  const float* rb = resp + (size_t)b * HW_;
  bool interior = (bx >= 1 && bx <= 14 && by >= 1 && by <= 14);
  if (interior) {
    // rows r0-2..r0+33, cols c0-4..c0+35 (aligned f32x4), 36 x 10 groups
    for (int l = tid; l < 360; l += 256) {
      int lr = l / 10, c4 = (l % 10) * 4;
      *(f32x4*)&r_s[lr][c4] = ld4(&rb[(r0 - 2 + lr) * W_ + (c0 - 4 + c4)]);
    }
  } else {
    for (int l = tid; l < 36 * 40; l += 256) {
      int lr = l / 40, lc = l % 40;
      int gr = r0 - 2 + lr, gc = c0 - 4 + lc;
      float v = -INFINITY;
      if (gr >= 0 && gr < H_ && gc >= 0 && gc < W_) v = rb[gr * W_ + gc];
      r_s[lr][lc] = v;
    }
  }
  __syncthreads();

  // row-max: rm[r][c] = max over r_s[r][c+2..c+6]  (center col = c+4)
  for (int l = tid; l < 1152; l += 256) {
    int r = l >> 5, c = l & 31;
    float m = fmaxf(fmaxf(fmaxf(r_s[r][c + 2], r_s[r][c + 3]),
                          fmaxf(r_s[r][c + 4], r_s[r][c + 5])),
                    r_s[r][c + 6]);
    rm_s[r][c] = m;
  }
  __syncthreads();

  // col-max + keep-if-equal (x == 5x5 maxpool)
  for (int l = tid; l < 1024; l += 256) {
    int r = l >> 5, c = l & 31;
    float m = fmaxf(fmaxf(fmaxf(rm_s[r][c], rm_s[r + 1][c]),
                          fmaxf(rm_s[r + 2][c], rm_s[r + 3][c])),
                    rm_s[r + 4][c]);
    float v = r_s[r + 2][c + 4];
    c_s[r][c] = (v == m) ? v : 0.f;
  }
  __syncthreads();

  // per-8x8-block max into deterministic cand slot (min-idx tiebreak)
  if (tid < 16) {
    int sr = (tid >> 2) << 3, sc_ = (tid & 3) << 3;
    float m = 0.f;
    int mi = INT_MAX;
#pragma unroll
    for (int u = 0; u < 8; u++)
      for (int w = 0; w < 8; w++) {
        float v = c_s[sr + u][sc_ + w];
        if (v > m) { m = v; mi = (r0 + sr + u) * W_ + (c0 + sc_ + w); }
      }
    int subg = ((r0 + sr) >> 3) * 64 + ((c0 + sc_) >> 3);
    bool pos = (m > 0.f);
    cand_val[b * CAP_ + subg] = pos ? m : -INFINITY;
    cand_idx[b * CAP_ + subg] = pos ? mi : INT_MAX;
  }

  // BCE base chunk reduce -> part[bid]
  float s = fmaxf(log1pf(-sc[0]), -100.f) + fmaxf(log1pf(-sc[1]), -100.f) +
            fmaxf(log1pf(-sc[2]), -100.f) + fmaxf(log1pf(-sc[3]), -100.f);
  for (int off = 32; off > 0; off >>= 1) s += __shfl_down(s, off);
  if ((tid & 63) == 0) wsum[tid >> 6] = s;
  __syncthreads();
  if (tid == 0) {
    double t = (double)wsum[0] + (double)wsum[1] + (double)wsum[2] + (double)wsum[3];
    part[bid] = t;  // deterministic slot, overwritten every call
  }
}

// K3: per-image top-500 via MSB-first RADIX SELECT (no sort) + fused FINAL
// REDUCE: the last block (done-counter, reset by k_resp) sums all partials
// and writes the loss. Items in registers (4/thread); 4 passes x 8 bits:
// LDS histogram + wave-0 parallel suffix-scan. Second nms2d is a provable
// no-op, so every selected positive item is a corner.
__global__ __launch_bounds__(1024) void k_select(const float* __restrict__ cand_val,
                                                 const int* __restrict__ cand_idx,
                                                 const float* __restrict__ scores,
                                                 double* __restrict__ part,
                                                 int* __restrict__ done,
                                                 float* __restrict__ out) {
  int b = blockIdx.x;
  __shared__ unsigned hist[256];
  __shared__ unsigned s_prefix;
  __shared__ int s_rank;
  __shared__ int eq_idx[1024];
  __shared__ int eq_cnt;
  __shared__ float wsum[16];
  __shared__ double dsum[16];
  __shared__ int s_last;
  int tid = threadIdx.x;

  unsigned key[4];
  int idx[4];
#pragma unroll
  for (int q = 0; q < 4; q++) {
    int l = tid + q * 1024;
    float v = cand_val[b * CAP_ + l];
    idx[q] = cand_idx[b * CAP_ + l];
    unsigned u = __float_as_uint(v);
    key[q] = (u & 0x80000000u) ? ~u : (u | 0x80000000u);  // order-preserving
  }
  if (tid == 0) { s_rank = NSEL_; s_prefix = 0; eq_cnt = 0; }

  for (int pass = 0; pass < 4; pass++) {
    int shift = 24 - 8 * pass;
    if (tid < 256) hist[tid] = 0;
    __syncthreads();
    unsigned pref = s_prefix;   // read-before-write: writes after next barrier
    int rank = s_rank;
#pragma unroll
    for (int q = 0; q < 4; q++) {
      bool match = (pass == 0) || ((key[q] >> (shift + 8)) == pref);
      if (match) atomicAdd(&hist[(key[q] >> shift) & 255u], 1u);
    }
    __syncthreads();
    if (tid < 64) {
      unsigned h0 = hist[tid * 4 + 0], h1 = hist[tid * 4 + 1];
      unsigned h2 = hist[tid * 4 + 2], h3 = hist[tid * 4 + 3];
      unsigned tot = h0 + h1 + h2 + h3;
      unsigned suf = tot;  // suffix sum over lanes >= tid
#pragma unroll
      for (int off = 1; off < 64; off <<= 1) {
        unsigned o = __shfl_down(suf, off);
        if (tid + off < 64) suf += o;
      }
      unsigned above3 = suf - tot;
      unsigned above2 = above3 + h3;
      unsigned above1 = above2 + h2;
      unsigned above0 = above1 + h1;
      unsigned r = (unsigned)rank;
      if (above0 < r && r <= above0 + h0) { s_rank = (int)(r - above0); s_prefix = (pref << 8) | (unsigned)(tid * 4 + 0); }
      if (above1 < r && r <= above1 + h1) { s_rank = (int)(r - above1); s_prefix = (pref << 8) | (unsigned)(tid * 4 + 1); }
      if (above2 < r && r <= above2 + h2) { s_rank = (int)(r - above2); s_prefix = (pref << 8) | (unsigned)(tid * 4 + 2); }
      if (above3 < r && r <= above3 + h3) { s_rank = (int)(r - above3); s_prefix = (pref << 8) | (unsigned)(tid * 4 + 3); }
    }
    __syncthreads();
  }
  unsigned T = s_prefix;
  int need = s_rank;

#pragma unroll
  for (int q = 0; q < 4; q++) {
    if (key[q] == T) {
      int pos = atomicAdd(&eq_cnt, 1);
      if (pos < 1024) eq_idx[pos] = idx[q];
    }
  }
  __syncthreads();
  int E = min(eq_cnt, 1024);

  const unsigned KPOS = 0x80000000u;  // key of +0.0; corners need value > 0
  float term = 0.f;
#pragma unroll
  for (int q = 0; q < 4; q++) {
    bool corner = false;
    if (key[q] > KPOS) {
      if (key[q] > T) {
        corner = true;
      } else if (key[q] == T) {
        int r = 0;
        for (int j = 0; j < E; j++) r += (eq_idx[j] < idx[q]);
        corner = (r < need);
      }
    }
    if (corner) {
      float p = scores[(size_t)b * HW_ + idx[q]];
      term += fmaxf(logf(p), -100.f) - fmaxf(log1pf(-p), -100.f);
    }
  }
  for (int off = 32; off > 0; off >>= 1) term += __shfl_down(term, off);
  if ((tid & 63) == 0) wsum[tid >> 6] = term;
  __syncthreads();
  if (tid == 0) {
    double s = 0.0;
    for (int i = 0; i < 16; i++) s += (double)wsum[i];
    // release-store our partial, then bump the done counter (acq_rel)
    __hip_atomic_store(&part[NTILE_ + b], s, __ATOMIC_RELEASE,
                       __HIP_MEMORY_SCOPE_AGENT);
    int old = __hip_atomic_fetch_add(done, 1, __ATOMIC_ACQ_REL,
                                     __HIP_MEMORY_SCOPE_AGENT);
    s_last = (old == B_ - 1) ? 1 : 0;
  }
  __syncthreads();
  if (!s_last) return;

  // FINAL REDUCE (last block only): k_nms partials are pre-kernel (plain
  // loads safe via dispatch acquire); sibling k_select partials via
  // atomic-acquire loads.
  double s = 0.0;
  for (int i = tid; i < NTILE_; i += 1024) s += part[i];
  if (tid < B_)
    s += __hip_atomic_load(&part[NTILE_ + tid], __ATOMIC_ACQUIRE,
                           __HIP_MEMORY_SCOPE_AGENT);
  for (int off = 32; off > 0; off >>= 1) s += __shfl_down(s, off);
  if ((tid & 63) == 0) dsum[tid >> 6] = s;
  __syncthreads();
  if (tid == 0) {
    double t = 0.0;
    for (int i = 0; i < 16; i++) t += dsum[i];
    out[0] = (float)(-t / (double)((size_t)B_ * HW_));
  }
}

}  // namespace

extern "C" void kernel_launch(void* const* d_in, const int* in_sizes, int n_in,
                              void* d_out, int out_size, void* d_ws, size_t ws_size,
                              hipStream_t stream) {
  const float* scores = (const float*)d_in[0];
  const float* imgs = (const float*)d_in[1];
  float* out = (float*)d_out;

  char* ws = (char*)d_ws;
  double* part = (double*)ws;                          // NPART_ doubles (32,896 B)
  int* done = (int*)(ws + 32896);                      // 4 B counter
  float* resp = (float*)(ws + 33024);                  // 16 MB, 16B-aligned
  float* cand_val = resp + (size_t)B_ * HW_;           // 16*4096 f32
  int* cand_idx = (int*)(cand_val + B_ * CAP_);        // 16*4096 i32

  k_resp<<<NTILE_, 256, 0, stream>>>(imgs, resp, done);
  k_nms<<<NTILE_, 256, 0, stream>>>(resp, scores, cand_val, cand_idx, part);
  k_select<<<B_, 1024, 0, stream>>>(cand_val, cand_idx, scores, part, done, out);
}